// Round 1
// baseline (58.373 us; speedup 1.0000x reference)
//
#include <hip/hip_runtime.h>

// ---------------------------------------------------------------------------
// LivingLooper forward:
//   1) ring-buffer record of z_in for active loop at rows (rec-dt)%M, dt=0..lc
//   2) window = mem1[rec-ctx .. rec-1]  -> flat [F], F = ctx*L*D
//   3) x = tanh((flat - center)*0.5)  [L,F]
//   4) z = einsum('lf,lfd->ld', x, W) + bias ; inv ; clip       <-- 256 MB, HBM-bound
//   5) scatter z into mem2[rec] for all loops except active; zs = mem2[rec]
//   6) y = y_audio * (mask1*fade + mask0*(1-fade))
// Outputs concatenated: y [L*BLK], zs [L*D], mem2 [M*L*D]
// ---------------------------------------------------------------------------

// Fused x-compute + matvec. Each block: one loop l, 256 consecutive f-rows.
// x slice -> LDS; W streamed as float4 (coalesced); LDS reduce; atomicAdd.
__global__ __launch_bounds__(256) void ll_matvec_kernel(
    const float* __restrict__ memory, const float* __restrict__ z_in,
    const float* __restrict__ weights, const float* __restrict__ center,
    const int* __restrict__ rec_p, const int* __restrict__ act_p,
    const int* __restrict__ lc_p, const int* __restrict__ ctx_p,
    float* __restrict__ zacc,
    int L, int D, int F, int n_memory, int blocksPerLoop)
{
    __shared__ float x_lds[256];
    __shared__ float ps[8 * 128];

    const int bid = blockIdx.x;
    const int l = bid / blocksPerLoop;
    const int chunk = bid - l * blocksPerLoop;
    const int f0 = chunk * 256;
    const int tid = threadIdx.x;

    const int rec = *rec_p;
    const int i_act = *act_p - 1;
    const int lc = *lc_p;
    const int ctx = *ctx_p;
    const int LD = L * D;

    // ---- compute x[f0 .. f0+255] into LDS ----
    {
        const int f = f0 + tid;
        const int c = f / LD;          // context index
        const int rem = f - c * LD;    // (loop, latent) within frame
        const int ll = rem / D;
        const int dd = rem - ll * D;
        int row = rec - ctx + c;
        row %= n_memory; if (row < 0) row += n_memory;
        int diff = rec - row; if (diff < 0) diff += n_memory; // (rec-row) mod M
        float v = (ll == i_act && diff <= lc)
                      ? z_in[dd]
                      : memory[(size_t)row * LD + rem];
        const float cen = center[(size_t)l * F + f];
        x_lds[tid] = tanhf((v - cen) * 0.5f);
    }
    __syncthreads();

    // ---- matvec: 8 groups of 32 lanes; group g does rows g, g+8, ... ----
    const int g = tid >> 5;
    const int t = tid & 31;
    const int d4 = t * 4;                 // D==128: 32 lanes * float4
    const float4* __restrict__ W =
        (const float4*)(weights + ((size_t)l * F + f0) * D);
    float4 acc = make_float4(0.f, 0.f, 0.f, 0.f);
    #pragma unroll 4
    for (int i = 0; i < 32; ++i) {
        const int r = i * 8 + g;
        const float xv = x_lds[r];                  // LDS broadcast in group
        const float4 w = W[(size_t)r * 32 + t];     // coalesced 512B/group
        acc.x += xv * w.x; acc.y += xv * w.y;
        acc.z += xv * w.z; acc.w += xv * w.w;
    }
    ps[g * 128 + d4 + 0] = acc.x;
    ps[g * 128 + d4 + 1] = acc.y;
    ps[g * 128 + d4 + 2] = acc.z;
    ps[g * 128 + d4 + 3] = acc.w;
    __syncthreads();

    if (tid < 128) {
        float s = 0.f;
        #pragma unroll
        for (int gg = 0; gg < 8; ++gg) s += ps[gg * 128 + tid];
        atomicAdd(&zacc[l * D + tid], s);
    }
}

// mem2 copy (all rows except record_index, with active-loop ring overrides)
// + audio crossfade.
__global__ __launch_bounds__(256) void ll_misc_kernel(
    const float* __restrict__ memory, const float* __restrict__ z_in,
    const float* __restrict__ mask, const float* __restrict__ y_audio,
    const int* __restrict__ rec_p, const int* __restrict__ act_p,
    const int* __restrict__ lc_p,
    float* __restrict__ out_y, float* __restrict__ out_mem2,
    int L, int D, int n_memory, int BLK)
{
    const int idx = blockIdx.x * blockDim.x + threadIdx.x;
    const int LD = L * D;
    const int Ncopy = n_memory * LD;
    if (idx < Ncopy) {
        const int rec = *rec_p;
        const int row = idx / LD;
        if (row == rec) return;            // finalize kernel owns this row
        const int rem = idx - row * LD;
        const int ll = rem / D;
        const int dd = rem - ll * D;
        int diff = rec - row; if (diff < 0) diff += n_memory;
        float v;
        if (ll == (*act_p - 1) && diff <= *lc_p) v = z_in[dd];
        else                                     v = memory[idx];
        out_mem2[idx] = v;
    } else if (idx < Ncopy + L * BLK) {
        const int j = idx - Ncopy;
        const int l = j / BLK;
        const int k = j - l * BLK;
        const float fade = (float)k / (float)(BLK - 1);
        const float m = mask[L + l] * fade + mask[l] * (1.f - fade);
        out_y[j] = y_audio[j] * m;
    }
}

// z finalize: bias, target_process_inv, clip; write zs and mem2[rec].
__global__ __launch_bounds__(256) void ll_finalize_kernel(
    const float* __restrict__ zacc, const float* __restrict__ bias,
    const float* __restrict__ z_min, const float* __restrict__ z_max,
    const float* __restrict__ limit_margin, const float* __restrict__ z_in,
    const int* __restrict__ rec_p, const int* __restrict__ act_p,
    float* __restrict__ out_zs, float* __restrict__ out_mem2,
    int L, int D)
{
    const int tid = blockIdx.x * blockDim.x + threadIdx.x;
    if (tid >= L * D) return;
    const int l = tid / D;
    const int d = tid - l * D;

    float z = zacc[tid] + bias[tid];
    const float hi = 2.f * sqrtf(fmaxf(z, 1.f)) - 1.f;
    const float lo = 1.f - 2.f * sqrtf(fmaxf(-z, 1.f));
    z = (z > 1.f) ? hi : ((z < -1.f) ? lo : z);
    const float zl = z_min[tid] - limit_margin[d];
    const float zh = z_max[tid] + limit_margin[d];
    z = fminf(fmaxf(z, zl), zh);

    const float out = (l == (*act_p - 1)) ? z_in[d] : z;
    out_zs[tid] = out;
    out_mem2[(size_t)(*rec_p) * (L * D) + tid] = out;
}

extern "C" void kernel_launch(void* const* d_in, const int* in_sizes, int n_in,
                              void* d_out, int out_size, void* d_ws, size_t ws_size,
                              hipStream_t stream) {
    const float* memory       = (const float*)d_in[0];
    const float* z_in         = (const float*)d_in[1];
    const float* weights      = (const float*)d_in[2];
    const float* center       = (const float*)d_in[3];
    const float* bias         = (const float*)d_in[4];
    const float* z_min        = (const float*)d_in[5];
    const float* z_max        = (const float*)d_in[6];
    const float* limit_margin = (const float*)d_in[7];
    const float* mask         = (const float*)d_in[8];
    const float* y_audio      = (const float*)d_in[9];
    const int*   rec_p        = (const int*)d_in[10];
    const int*   act_p        = (const int*)d_in[11];
    const int*   lc_p         = (const int*)d_in[12];
    const int*   ctx_p        = (const int*)d_in[13];

    const int D        = in_sizes[1];            // 128
    const int L        = in_sizes[4] / D;        // 8
    const int LD       = L * D;                  // 1024
    const int n_memory = in_sizes[0] / LD;       // 1067
    const int F        = in_sizes[3] / L;        // 65536
    const int BLK      = in_sizes[9] / L;        // 2048

    float* out_y    = (float*)d_out;             // [L*BLK]
    float* out_zs   = out_y + (size_t)L * BLK;   // [LD]
    float* out_mem2 = out_zs + LD;               // [n_memory*LD]

    float* zacc = (float*)d_ws;                  // [LD] accumulator
    hipMemsetAsync(zacc, 0, (size_t)LD * sizeof(float), stream);

    const int blocksPerLoop = F / 256;           // 256
    ll_matvec_kernel<<<L * blocksPerLoop, 256, 0, stream>>>(
        memory, z_in, weights, center, rec_p, act_p, lc_p, ctx_p,
        zacc, L, D, F, n_memory, blocksPerLoop);

    const int total = n_memory * LD + L * BLK;
    ll_misc_kernel<<<(total + 255) / 256, 256, 0, stream>>>(
        memory, z_in, mask, y_audio, rec_p, act_p, lc_p,
        out_y, out_mem2, L, D, n_memory, BLK);

    ll_finalize_kernel<<<(LD + 255) / 256, 256, 0, stream>>>(
        zacc, bias, z_min, z_max, limit_margin, z_in,
        rec_p, act_p, out_zs, out_mem2, L, D);
}